// Round 2
// baseline (312.801 us; speedup 1.0000x reference)
//
#include <hip/hip_runtime.h>
#include <hip/hip_bf16.h>

#define DEVI __device__ __forceinline__

typedef __attribute__((ext_vector_type(8))) short short8;
typedef __attribute__((ext_vector_type(8))) unsigned short ushort8;
typedef __attribute__((ext_vector_type(4))) float f32x4;

// problem constants
static constexpr int BB = 32, TT = 64, KIN = 4894, KINP = 4896;
static constexpr int E = 128, NG = 768;

DEVI unsigned short f2bf(float f) {
    union { float f; unsigned u; } v; v.f = f;
    unsigned r = v.u + 0x7fffu + ((v.u >> 16) & 1u);
    return (unsigned short)(r >> 16);
}
DEVI float sigm(float x) { return __builtin_amdgcn_rcpf(1.f + __expf(-x)); }
DEVI float tanh_(float x) { return 1.f - 2.f * __builtin_amdgcn_rcpf(__expf(2.f * x) + 1.f); }

// ---------------- prep: weight casts / padding only ----------------
__global__ void prep_kernel(const float* __restrict__ Wemb,
                            const float* __restrict__ Wih_a, const float* __restrict__ Wih_b,
                            const float* __restrict__ Whh_a, const float* __restrict__ Whh_b,
                            const float* __restrict__ Wbeta,
                            unsigned short* __restrict__ wembbf,
                            unsigned short* __restrict__ wihbf, unsigned short* __restrict__ whhbf,
                            unsigned short* __restrict__ wbetabf, float* __restrict__ col128) {
    int job = blockIdx.x * blockDim.x + threadIdx.x;
    const int JWE = 128 * 612, JWIH = 768 * 16, JWHH = 768 * 16, JWB = 128 * 16, JCOL = 96;
    if (job < JWE) {
        int row = job / 612, c8 = (job % 612) * 8;
        ushort8 v;
        #pragma unroll
        for (int jj = 0; jj < 8; ++jj) { int c = c8 + jj; v[jj] = (c < KIN) ? f2bf(Wemb[(long)row * KIN + c]) : (unsigned short)0; }
        *(ushort8*)(wembbf + (long)row * KINP + c8) = v;
        return;
    }
    job -= JWE;
    if (job < JWIH) {
        int g = job / 16, c8 = (job % 16) * 8;
        const float* src = (g < 384) ? (Wih_a + (long)g * 129) : (Wih_b + (long)(g - 384) * 129);
        ushort8 v;
        #pragma unroll
        for (int jj = 0; jj < 8; ++jj) v[jj] = f2bf(src[c8 + jj]);
        *(ushort8*)(wihbf + (long)g * 128 + c8) = v;
        return;
    }
    job -= JWIH;
    if (job < JWHH) {
        int g = job / 16, c8 = (job % 16) * 8;
        const float* src = (g < 384) ? (Whh_a + (long)g * 128) : (Whh_b + (long)(g - 384) * 128);
        ushort8 v;
        #pragma unroll
        for (int jj = 0; jj < 8; ++jj) v[jj] = f2bf(src[c8 + jj]);
        *(ushort8*)(whhbf + (long)g * 128 + c8) = v;
        return;
    }
    job -= JWHH;
    if (job < JWB) {
        int e = job / 16, c8 = (job % 16) * 8;
        ushort8 v;
        #pragma unroll
        for (int jj = 0; jj < 8; ++jj) v[jj] = f2bf(Wbeta[(long)e * 128 + c8 + jj]);
        *(ushort8*)(wbetabf + (long)e * 128 + c8) = v;
        return;
    }
    job -= JWB;
    if (job < JCOL) {
        int g0 = job * 8;
        #pragma unroll
        for (int jj = 0; jj < 8; ++jj) {
            int g = g0 + jj;
            col128[g] = (g < 384) ? Wih_a[(long)g * 129 + 128] : Wih_b[(long)(g - 384) * 129 + 128];
        }
    }
}

// ---------------- emb = x @ Wemb^T  (x f32 loaded directly, converted in-reg) ----------------
__global__ __launch_bounds__(256) void emb_gemm(const float* __restrict__ x,
                                                const unsigned short* __restrict__ wembbf,
                                                float* __restrict__ emb, unsigned short* __restrict__ embbf) {
    const int m0 = blockIdx.x * 16;
    const int w = threadIdx.x >> 6, l = threadIdx.x & 63, lr = l & 15, lo = l >> 4;
    const int n0 = (2 * w) * 16 + lr, n1 = (2 * w + 1) * 16 + lr;
    const float* xrow = x + (long)(m0 + lr) * KIN;
    f32x4 acc0 = {0, 0, 0, 0}, acc1 = {0, 0, 0, 0};
    #pragma unroll 4
    for (int kt = 0; kt < 152; ++kt) {
        int k = kt * 32 + lo * 8;
        float2 x0 = *(const float2*)(xrow + k);
        float2 x1 = *(const float2*)(xrow + k + 2);
        float2 x2 = *(const float2*)(xrow + k + 4);
        float2 x3 = *(const float2*)(xrow + k + 6);
        short8 a;
        a[0] = (short)f2bf(x0.x); a[1] = (short)f2bf(x0.y);
        a[2] = (short)f2bf(x1.x); a[3] = (short)f2bf(x1.y);
        a[4] = (short)f2bf(x2.x); a[5] = (short)f2bf(x2.y);
        a[6] = (short)f2bf(x3.x); a[7] = (short)f2bf(x3.y);
        short8 b0 = *(const short8*)(wembbf + (long)n0 * KINP + k);
        short8 b1 = *(const short8*)(wembbf + (long)n1 * KINP + k);
        acc0 = __builtin_amdgcn_mfma_f32_16x16x32_bf16(a, b0, acc0, 0, 0, 0);
        acc1 = __builtin_amdgcn_mfma_f32_16x16x32_bf16(a, b1, acc1, 0, 0, 0);
    }
    { // tail k-tile (kt=152): guard the last 2 columns (4894,4895)
        int k = 4864 + lo * 8;
        short8 a;
        #pragma unroll
        for (int jj = 0; jj < 8; ++jj) { int c = k + jj; a[jj] = (c < KIN) ? (short)f2bf(xrow[c]) : (short)0; }
        short8 b0 = *(const short8*)(wembbf + (long)n0 * KINP + k);
        short8 b1 = *(const short8*)(wembbf + (long)n1 * KINP + k);
        acc0 = __builtin_amdgcn_mfma_f32_16x16x32_bf16(a, b0, acc0, 0, 0, 0);
        acc1 = __builtin_amdgcn_mfma_f32_16x16x32_bf16(a, b1, acc1, 0, 0, 0);
    }
    #pragma unroll
    for (int r = 0; r < 4; ++r) {
        int m = m0 + lo * 4 + r;
        emb[(long)m * E + n0] = acc0[r];
        emb[(long)m * E + n1] = acc1[r];
        embbf[(long)m * E + n0] = f2bf(acc0[r]);
        embbf[(long)m * E + n1] = f2bf(acc1[r]);
    }
}

// ---------------- Gi3 = temb @ Wih^T + bih + bhh(r,z), repacked [tok][gru][u][r,z,n,pad] ----------------
__global__ __launch_bounds__(256) void gi_gemm(const unsigned short* __restrict__ embbf,
                                               const unsigned short* __restrict__ wihbf,
                                               const float* __restrict__ t,
                                               const float* __restrict__ bih_a, const float* __restrict__ bih_b,
                                               const float* __restrict__ bhh_a, const float* __restrict__ bhh_b,
                                               const float* __restrict__ col128, float* __restrict__ Gi3) {
    const int m0 = blockIdx.x * 32;
    const int w = threadIdx.x >> 6, l = threadIdx.x & 63, lr = l & 15, lo = l >> 4;
    f32x4 acc[2][12];
    #pragma unroll
    for (int mt = 0; mt < 2; ++mt)
        #pragma unroll
        for (int nl = 0; nl < 12; ++nl) acc[mt][nl] = (f32x4){0, 0, 0, 0};
    #pragma unroll
    for (int kt = 0; kt < 4; ++kt) {
        int k = kt * 32 + lo * 8;
        short8 a0 = *(const short8*)(embbf + (long)(m0 + lr) * E + k);
        short8 a1 = *(const short8*)(embbf + (long)(m0 + 16 + lr) * E + k);
        #pragma unroll
        for (int nl = 0; nl < 12; ++nl) {
            int n = (w * 12 + nl) * 16 + lr;
            short8 bf = *(const short8*)(wihbf + (long)n * 128 + k);
            acc[0][nl] = __builtin_amdgcn_mfma_f32_16x16x32_bf16(a0, bf, acc[0][nl], 0, 0, 0);
            acc[1][nl] = __builtin_amdgcn_mfma_f32_16x16x32_bf16(a1, bf, acc[1][nl], 0, 0, 0);
        }
    }
    #pragma unroll
    for (int mt = 0; mt < 2; ++mt)
        #pragma unroll
        for (int nl = 0; nl < 12; ++nl) {
            int n = (w * 12 + nl) * 16 + lr;      // 0..767
            int gru = n >> 8 >= 1 ? (n >= 384 ? 1 : 0) : (n >= 384 ? 1 : 0);
            gru = (n >= 384) ? 1 : 0;
            int nn = n - gru * 384;
            int gt = nn >> 7, u = nn & 127;
            float bias = (gru ? bih_b[nn] : bih_a[nn]);
            if (gt < 2) bias += (gru ? bhh_b[nn] : bhh_a[nn]);
            float cw = col128[n];
            #pragma unroll
            for (int r = 0; r < 4; ++r) {
                int tok = m0 + mt * 16 + lo * 4 + r;
                Gi3[((long)(tok * 2 + gru) * 128 + u) * 4 + gt] = acc[mt][nl][r] + bias + t[tok] * cw;
            }
        }
}

// ---------------- recurrence + online-softmax attention (1 barrier / step) ----------------
// 128 blocks = (i 0..63) x (q 0..1); 16 chains/block; 8 waves; gru = w>>2.
// Pipeline: iter k computes gh_k/gates_k (H_{k-1}->H_k), beta/score of H_{k-1} (lag 1),
// attention accumulation of step k-2 (lag 2). Double-buffered Hbf -> single barrier.
__global__ __launch_bounds__(512) void retain_rec(
    const unsigned short* __restrict__ whhbf, const unsigned short* __restrict__ wbetabf,
    const float* __restrict__ Gi3, const float* __restrict__ emb,
    const float* __restrict__ bhh_a, const float* __restrict__ bhh_b,
    const float* __restrict__ w_alpha, const float* __restrict__ b_alpha,
    const float* __restrict__ b_beta, const float* __restrict__ Wout,
    const float* __restrict__ b_out, const int* __restrict__ lengths,
    float* __restrict__ out) {
    const int tid = threadIdx.x;
    const int w = tid >> 6, l = tid & 63, lr = l & 15, lo = l >> 4;
    const int i = blockIdx.x >> 1, q = blockIdx.x & 1;
    const int gru = w >> 2;
    const int ubase = (w & 3) * 32;

    __shared__ __align__(16) unsigned short Hbf[2][2][16][128]; // [buf][gru][c][u ^ ((c&7)*8)]
    __shared__ float fac_s[2][16], p_s[2][16];
    __shared__ float l_s[16];
    __shared__ float red_s[16][64];

    for (int idx = tid; idx < 2 * 16 * 128; idx += 512) (&Hbf[0][0][0][0])[idx] = 0; // H_{-1}=0

    // persistent Whh B-fragments
    short8 Wf[6][4];
    #pragma unroll
    for (int utl = 0; utl < 2; ++utl)
        #pragma unroll
        for (int gt = 0; gt < 3; ++gt)
            #pragma unroll
            for (int kt = 0; kt < 4; ++kt) {
                int n = gru * 384 + gt * 128 + ubase + utl * 16 + lr;
                Wf[utl * 3 + gt][kt] = *(const short8*)(whhbf + (long)n * 128 + kt * 32 + lo * 8);
            }
    // extra B tiles: waves 4-7 -> 2 beta tiles; wave 0 -> score tile (col0 = w_alpha)
    short8 Xf[2][4];
    #pragma unroll
    for (int tl = 0; tl < 2; ++tl)
        #pragma unroll
        for (int kt = 0; kt < 4; ++kt) {
            short8 z;
            #pragma unroll
            for (int jj = 0; jj < 8; ++jj) z[jj] = 0;
            Xf[tl][kt] = z;
        }
    if (w >= 4) {
        #pragma unroll
        for (int tl = 0; tl < 2; ++tl)
            #pragma unroll
            for (int kt = 0; kt < 4; ++kt) {
                int et = (w - 4) * 2 + tl;
                Xf[tl][kt] = *(const short8*)(wbetabf + (long)(et * 16 + lr) * 128 + kt * 32 + lo * 8);
            }
    } else if (w == 0 && lr == 0) {
        #pragma unroll
        for (int kt = 0; kt < 4; ++kt)
            #pragma unroll
            for (int jj = 0; jj < 8; ++jj)
                Xf[0][kt][jj] = (short)f2bf(w_alpha[kt * 32 + lo * 8 + jj]);
    }

    const float* bhh_g = gru ? bhh_b : bhh_a;
    const float bhn0 = bhh_g[256 + ubase + lr];
    const float bhn1 = bhh_g[256 + ubase + 16 + lr];
    float bbeta0 = 0.f, bbeta1 = 0.f;
    if (w >= 4) { bbeta0 = b_beta[(w - 4) * 32 + lr]; bbeta1 = b_beta[(w - 4) * 32 + 16 + lr]; }
    const float balpha0 = b_alpha[0];

    float h_old[2][4] = {{0, 0, 0, 0}, {0, 0, 0, 0}};
    float accv0[4] = {0, 0, 0, 0}, accv1[4] = {0, 0, 0, 0};
    f32x4 xacc_prev0 = {0, 0, 0, 0}, xacc_prev1 = {0, 0, 0, 0};
    float m0r[4] = {-1e30f, -1e30f, -1e30f, -1e30f};
    float lsum[4] = {0, 0, 0, 0};

    __syncthreads();

    const int iend = i + 2;
    for (int k = 0; k <= iend; ++k) {
        const int rb = k & 1, wb = rb ^ 1;
        const bool do_gru = (k <= i);
        const bool kx = (k >= 1 && k <= i + 1);
        const bool do_x = kx && (w >= 4 || w == 0);
        const bool do_accv = (k >= 2) && (w >= 4);
        const int j = i - k;
        const int jat = j + 2; // token for step k-2

        // ---- global prefetch for this iteration ----
        f32x4 giv[2][4];
        if (do_gru) {
            #pragma unroll
            for (int utl = 0; utl < 2; ++utl)
                #pragma unroll
                for (int r = 0; r < 4; ++r) {
                    int c = lo * 4 + r;
                    int tok = (q * 16 + c) * 64 + j;
                    giv[utl][r] = *(const f32x4*)(Gi3 + ((long)(tok * 2 + gru) * 128 + ubase + utl * 16 + lr) * 4);
                }
        }
        float ev_c[2][4];
        if (do_accv) {
            #pragma unroll
            for (int tl = 0; tl < 2; ++tl)
                #pragma unroll
                for (int r = 0; r < 4; ++r) {
                    int c = lo * 4 + r;
                    int tok = (q * 16 + c) * 64 + jat;
                    ev_c[tl][r] = emb[(long)tok * E + (w - 4) * 32 + tl * 16 + lr];
                }
        }

        // ---- LDS A-frags + MFMA ----
        f32x4 gh0, gh1, gh2, gh3, gh4, gh5;
        f32x4 xacc0 = {0, 0, 0, 0}, xacc1 = {0, 0, 0, 0};
        if (do_gru || do_x) {
            short8 Af[4];
            #pragma unroll
            for (int kt = 0; kt < 4; ++kt) {
                int sw = (kt * 32 + lo * 8) ^ ((lr & 7) * 8);
                Af[kt] = *(const short8*)(&Hbf[rb][gru][lr][sw]);
            }
            if (do_gru) {
                gh0 = (f32x4){0, 0, 0, 0}; gh1 = (f32x4){0, 0, 0, 0};
                gh2 = (f32x4){bhn0, bhn0, bhn0, bhn0};
                gh3 = (f32x4){0, 0, 0, 0}; gh4 = (f32x4){0, 0, 0, 0};
                gh5 = (f32x4){bhn1, bhn1, bhn1, bhn1};
                #pragma unroll
                for (int kt = 0; kt < 4; ++kt) {
                    gh0 = __builtin_amdgcn_mfma_f32_16x16x32_bf16(Af[kt], Wf[0][kt], gh0, 0, 0, 0);
                    gh1 = __builtin_amdgcn_mfma_f32_16x16x32_bf16(Af[kt], Wf[1][kt], gh1, 0, 0, 0);
                    gh2 = __builtin_amdgcn_mfma_f32_16x16x32_bf16(Af[kt], Wf[2][kt], gh2, 0, 0, 0);
                    gh3 = __builtin_amdgcn_mfma_f32_16x16x32_bf16(Af[kt], Wf[3][kt], gh3, 0, 0, 0);
                    gh4 = __builtin_amdgcn_mfma_f32_16x16x32_bf16(Af[kt], Wf[4][kt], gh4, 0, 0, 0);
                    gh5 = __builtin_amdgcn_mfma_f32_16x16x32_bf16(Af[kt], Wf[5][kt], gh5, 0, 0, 0);
                }
            }
            if (do_x) {
                #pragma unroll
                for (int kt = 0; kt < 4; ++kt)
                    xacc0 = __builtin_amdgcn_mfma_f32_16x16x32_bf16(Af[kt], Xf[0][kt], xacc0, 0, 0, 0);
                if (w >= 4) {
                    #pragma unroll
                    for (int kt = 0; kt < 4; ++kt)
                        xacc1 = __builtin_amdgcn_mfma_f32_16x16x32_bf16(Af[kt], Xf[1][kt], xacc1, 0, 0, 0);
                }
                // wave 0: online softmax scalars for step k-1
                if (w == 0 && lr == 0) {
                    #pragma unroll
                    for (int r = 0; r < 4; ++r) {
                        int c = lo * 4 + r;
                        float s = xacc0[r] + balpha0;
                        float mn = fmaxf(m0r[r], s);
                        float fac = __expf(m0r[r] - mn);
                        float p = __expf(s - mn);
                        lsum[r] = lsum[r] * fac + p;
                        m0r[r] = mn;
                        fac_s[k & 1][c] = fac;
                        p_s[k & 1][c] = p;
                    }
                }
            }
        }

        // ---- gates: H_k = GRU(H_{k-1}, x_j) ----
        if (do_gru) {
            #pragma unroll
            for (int utl = 0; utl < 2; ++utl) {
                #pragma unroll
                for (int r = 0; r < 4; ++r) {
                    f32x4 g = giv[utl][r];
                    float ghr = (utl ? gh3[r] : gh0[r]);
                    float ghz = (utl ? gh4[r] : gh1[r]);
                    float ghn = (utl ? gh5[r] : gh2[r]);
                    float rr = sigm(g[0] + ghr);
                    float zz = sigm(g[1] + ghz);
                    float nn = tanh_(g[2] + rr * ghn);
                    float h = nn + zz * (h_old[utl][r] - nn);
                    h_old[utl][r] = h;
                    int c = lo * 4 + r;
                    int u = ubase + utl * 16 + lr;
                    Hbf[wb][gru][c][u ^ ((c & 7) * 8)] = f2bf(h);
                }
            }
        }

        // ---- attention accumulation for step k-2 ----
        if (do_accv) {
            int sl = (k + 1) & 1;
            #pragma unroll
            for (int r = 0; r < 4; ++r) {
                int c = lo * 4 + r;
                float fac = fac_s[sl][c], p = p_s[sl][c];
                float beta0 = tanh_(xacc_prev0[r] + bbeta0);
                float beta1 = tanh_(xacc_prev1[r] + bbeta1);
                accv0[r] = accv0[r] * fac + p * beta0 * ev_c[0][r];
                accv1[r] = accv1[r] * fac + p * beta1 * ev_c[1][r];
            }
        }
        if (do_x && w >= 4) { xacc_prev0 = xacc0; xacc_prev1 = xacc1; }

        __syncthreads();
    }

    // ---- output ----
    if (w == 0 && lr == 0) {
        #pragma unroll
        for (int r = 0; r < 4; ++r) l_s[lo * 4 + r] = lsum[r];
    }
    if (w >= 4) {
        float wo0 = Wout[(w - 4) * 32 + lr], wo1 = Wout[(w - 4) * 32 + 16 + lr];
        #pragma unroll
        for (int r = 0; r < 4; ++r) {
            int c = lo * 4 + r;
            red_s[c][(w - 4) * 16 + lr] = accv0[r] * wo0 + accv1[r] * wo1;
        }
    }
    __syncthreads();
    if (w == 0) {
        int c = l >> 2, ch = l & 3;
        float s = 0.f;
        #pragma unroll
        for (int tt = 0; tt < 16; ++tt) s += red_s[c][ch * 16 + tt];
        s += __shfl_xor(s, 1);
        s += __shfl_xor(s, 2);
        if (ch == 0) {
            int b = q * 16 + c;
            float val = s / l_s[c] + b_out[0];
            if (i >= lengths[b]) val = b_out[0];
            out[b * TT + i] = val;
        }
    }
}

// ---------------- launch ----------------
extern "C" void kernel_launch(void* const* d_in, const int* in_sizes, int n_in,
                              void* d_out, int out_size, void* d_ws, size_t ws_size,
                              hipStream_t stream) {
    (void)in_sizes; (void)n_in; (void)out_size; (void)ws_size;
    const float* x       = (const float*)d_in[0];
    const float* t       = (const float*)d_in[1];
    const int*   len     = (const int*)d_in[2];
    const float* Wemb    = (const float*)d_in[3];
    const float* Wih_a   = (const float*)d_in[4];
    const float* Whh_a   = (const float*)d_in[5];
    const float* bih_a   = (const float*)d_in[6];
    const float* bhh_a   = (const float*)d_in[7];
    const float* Wih_b   = (const float*)d_in[8];
    const float* Whh_b   = (const float*)d_in[9];
    const float* bih_b   = (const float*)d_in[10];
    const float* bhh_b   = (const float*)d_in[11];
    const float* w_alpha = (const float*)d_in[12];
    const float* b_alpha = (const float*)d_in[13];
    const float* W_beta  = (const float*)d_in[14];
    const float* b_beta  = (const float*)d_in[15];
    const float* W_out   = (const float*)d_in[16];
    const float* b_out   = (const float*)d_in[17];

    char* ws = (char*)d_ws;
    float*          emb     = (float*)(ws + 0);                 // 1,048,576
    unsigned short* embbf   = (unsigned short*)(ws + 1048576);  //   524,288
    float*          Gi3     = (float*)(ws + 1572864);           // 8,388,608 (tok x gru x u x 4)
    unsigned short* wembbf  = (unsigned short*)(ws + 9961472);  // 1,253,376
    unsigned short* wihbf   = (unsigned short*)(ws + 11214848); //   196,608
    unsigned short* whhbf   = (unsigned short*)(ws + 11411456); //   196,608
    unsigned short* wbetabf = (unsigned short*)(ws + 11608064); //    32,768
    float*          col128  = (float*)(ws + 11640832);          //     3,072

    const int jobs = 128 * 612 + 768 * 16 + 768 * 16 + 128 * 16 + 96; // 105,056
    const int prep_blocks = (jobs + 255) / 256;

    prep_kernel<<<prep_blocks, 256, 0, stream>>>(Wemb, Wih_a, Wih_b, Whh_a, Whh_b, W_beta,
                                                 wembbf, wihbf, whhbf, wbetabf, col128);
    emb_gemm<<<128, 256, 0, stream>>>(x, wembbf, emb, embbf);
    gi_gemm<<<64, 256, 0, stream>>>(embbf, wihbf, t, bih_a, bih_b, bhh_a, bhh_b, col128, Gi3);
    retain_rec<<<128, 512, 0, stream>>>(whhbf, wbetabf, Gi3, emb, bhh_a, bhh_b,
                                        w_alpha, b_alpha, b_beta, W_out, b_out, len, (float*)d_out);
}